// Round 11
// baseline (296.187 us; speedup 1.0000x reference)
//
#include <hip/hip_runtime.h>
#include <math.h>

#define B_      16
#define CIN     256
#define HW_     4096          // 64x64
#define PLANES  256
#define G_      8
#define EPSV    1e-5f

typedef unsigned short u16;
typedef __attribute__((ext_vector_type(8))) short short8;   // 8 bf16 (4 VGPRs)
typedef __attribute__((ext_vector_type(4))) float f32x4;    // MFMA acc

__device__ inline u16 f2bf(float f) {
    union { float f; unsigned u; } v; v.f = f;
    unsigned u = v.u;
    return (u16)((u + 0x7fffu + ((u >> 16) & 1u)) >> 16);   // RNE
}
__device__ inline float bf2f(u16 h) {
    union { unsigned u; float f; } v; v.u = ((unsigned)h) << 16;
    return v.f;
}

// ---------------------------------------------------------------------------
// Kernel 0a: pack Wt|Wp|Wg (512x256 f32) into MFMA A-fragment order, split
// into bf16 hi + lo (w = hi + lo, exact to ~2^-16 rel).
// slot (rt 0..3, kt 0..7, mb 0..7, lane 0..63, j 0..7):
//   row = rt*128 + mb*16 + (lane&15); k = kt*32 + (lane>>4)*8 + j
// ---------------------------------------------------------------------------
__global__ __launch_bounds__(256) void k_packA(
    const float* __restrict__ Wt, const float* __restrict__ Wp,
    const float* __restrict__ Wg,
    u16* __restrict__ pAhi, u16* __restrict__ pAlo)
{
    int t = blockIdx.x * 256 + threadIdx.x;      // 0..16383
    int lane = t & 63;
    int mb   = (t >> 6) & 7;
    int kt   = (t >> 9) & 7;
    int rt   = (t >> 12) & 3;
    int row = rt * 128 + mb * 16 + (lane & 15);
    int k0  = kt * 32 + (lane >> 4) * 8;
    const float* src;
    if      (row < 256) src = Wt + (size_t)row * 256;
    else if (row < 384) src = Wp + (size_t)(row - 256) * 256;
    else                src = Wg + (size_t)(row - 384) * 256;
    u16 hv[8], lv[8];
    #pragma unroll
    for (int j = 0; j < 8; ++j) {
        float w = src[k0 + j];
        u16 h = f2bf(w);
        hv[j] = h;
        lv[j] = f2bf(w - bf2f(h));
    }
    *(short8*)(pAhi + (size_t)t * 8) = *(short8*)hv;
    *(short8*)(pAlo + (size_t)t * 8) = *(short8*)lv;
}

// ---------------------------------------------------------------------------
// Kernel 0b: transpose x[b][256][4096] f32 -> xThi/xTlo[b][4096][256]
// bf16 hi/lo split.  FULL batch, one launch (4096 blocks).
// ---------------------------------------------------------------------------
__global__ __launch_bounds__(256) void k_transpose(
    const float* __restrict__ x, u16* __restrict__ xThi,
    u16* __restrict__ xTlo)
{
    __shared__ float tile[32][129];
    int tid = threadIdx.x;
    int px0 = blockIdx.x * 128;
    int c0  = blockIdx.y * 32;
    int bg  = blockIdx.z;

    #pragma unroll
    for (int it = 0; it < 16; ++it) {
        int flat = it * 256 + tid;
        int c_l = flat >> 7, p_l = flat & 127;
        tile[c_l][p_l] = x[((size_t)bg * 256 + c0 + c_l) * 4096 + px0 + p_l];
    }
    __syncthreads();
    #pragma unroll
    for (int it = 0; it < 8; ++it) {
        int flat = it * 256 + tid;          // 0..2047
        int p_l = flat >> 4;
        int c_l = (flat & 15) * 2;
        float v0 = tile[c_l][p_l], v1 = tile[c_l + 1][p_l];
        u16 h0 = f2bf(v0), h1 = f2bf(v1);
        u16 l0 = f2bf(v0 - bf2f(h0)), l1 = f2bf(v1 - bf2f(h1));
        size_t o = ((size_t)bg * 4096 + px0 + p_l) * 256 + c0 + c_l;
        u16 ho[2] = { h0, h1 };
        u16 lo[2] = { l0, l1 };
        *(unsigned*)(xThi + o) = *(unsigned*)ho;
        *(unsigned*)(xTlo + o) = *(unsigned*)lo;
    }
}

// ---------------------------------------------------------------------------
// Kernel 1: tmod + zero att/stats
// ---------------------------------------------------------------------------
__global__ __launch_bounds__(256) void k_tmod_zero(
    const float* __restrict__ mask, const float* __restrict__ Wtm,
    float* __restrict__ tmod, float* __restrict__ att, float* __restrict__ stats)
{
    int idx = blockIdx.x * 256 + threadIdx.x;
    float w0 = Wtm[0], w1 = Wtm[1];
    if (idx < B_ * HW_) {
        int b = idx >> 12, pix = idx & 4095;
        const float* mb = mask + (size_t)b * 2 * HW_;
        tmod[idx] = 1.0f + w0 * mb[pix] + w1 * mb[HW_ + pix];
    }
    if (blockIdx.x == 0) {
        if (threadIdx.x < 128) att[threadIdx.x] = 0.0f;
        stats[threadIdx.x] = 0.0f;
    }
}

// ---------------------------------------------------------------------------
// Shared GEMM building blocks.  Block: 256 rows x 64 px, 4 waves stacked
// vertically (each wave 64 rows x 64 px).  32 KB LDS B-panel (XOR-swizzled).
// __launch_bounds__(256,4) caps VGPR at 128 -> 4 blocks/CU resident.
// A addressing: per-wave byte base aB = rt*65536 + mbb*1024 + lane*16;
// fragment (kt,m) at aB + kt*8192 + m*1024 (compile-time offsets).
// ---------------------------------------------------------------------------
#define STAGE8(SRC)                                                           \
    _Pragma("unroll")                                                         \
    for (int it = 0; it < 8; ++it) {                                          \
        int cidx = it * 256 + tid;                                            \
        int px   = cidx >> 5;                                                 \
        int boff = (cidx & 31) << 4;                                          \
        short8 v = *(const short8*)((SRC) + (size_t)px * 512 + boff);         \
        *(short8*)(Blds + px * 512 + (boff ^ ((px & 7) << 4))) = v;           \
    }

#define MFMA_PASS(ABASE)                                                      \
    _Pragma("unroll")                                                         \
    for (int kt = 0; kt < 8; ++kt) {                                          \
        short8 a[4], bb[4];                                                   \
        _Pragma("unroll")                                                     \
        for (int m = 0; m < 4; ++m)                                           \
            a[m] = *(const short8*)((ABASE) + kt * 8192 + m * 1024);          \
        int off = ((kt * 64) + ((lane >> 4) << 4)) ^ ((lane & 7) << 4);       \
        _Pragma("unroll")                                                     \
        for (int n = 0; n < 4; ++n) {                                         \
            int px = n * 16 + (lane & 15);                                    \
            bb[n] = *(const short8*)(Blds + px * 512 + off);                  \
        }                                                                     \
        _Pragma("unroll")                                                     \
        for (int m = 0; m < 4; ++m)                                           \
            _Pragma("unroll")                                                 \
            for (int n = 0; n < 4; ++n)                                       \
                acc[m][n] = __builtin_amdgcn_mfma_f32_16x16x32_bf16(          \
                    a[m], bb[n], acc[m][n], 0, 0, 0);                         \
    }

// ---------------------------------------------------------------------------
// Kernel 2a: t-GEMM, FULL batch, 1 bf16 pass -> bf16 tbuf (* tmod).
// Grid (64 px-tiles, 16 b) = 1024 blocks; block = 256 t-rows x 64 px.
// ---------------------------------------------------------------------------
__global__ __launch_bounds__(256, 4) void k_mm0(
    const u16* __restrict__ xThi, const u16* __restrict__ pAhi,
    const float* __restrict__ tmod, u16* __restrict__ tbuf)
{
    __shared__ short8 BldsV[2048];           // 32 KB
    char* Blds = (char*)BldsV;
    int tid = threadIdx.x, lane = tid & 63, wid = tid >> 6;
    int rt  = wid >> 1;                      // 0..1 (t row tiles)
    int mbb = (wid & 1) * 4;
    int pix0 = blockIdx.x * 64;
    int bg   = blockIdx.y;

    const char* srcHi = (const char*)(xThi + ((size_t)bg * 4096 + pix0) * 256);
    const char* aHi = (const char*)pAhi + rt * 65536 + mbb * 1024 + lane * 16;

    f32x4 acc[4][4];
    #pragma unroll
    for (int m = 0; m < 4; ++m)
        #pragma unroll
        for (int n = 0; n < 4; ++n) acc[m][n] = (f32x4)0.0f;

    STAGE8(srcHi);
    __syncthreads();
    MFMA_PASS(aHi);

    float tm[4];
    #pragma unroll
    for (int n = 0; n < 4; ++n) tm[n] = tmod[bg * 4096 + pix0 + n * 16 + (lane & 15)];
    #pragma unroll
    for (int m = 0; m < 4; ++m)
        #pragma unroll
        for (int n = 0; n < 4; ++n)
            #pragma unroll
            for (int r = 0; r < 4; ++r) {
                int row = wid * 64 + m * 16 + (lane >> 4) * 4 + r;   // 0..255
                int col = pix0 + n * 16 + (lane & 15);
                tbuf[((size_t)bg * 256 + row) * 4096 + col] = f2bf(acc[m][n][r] * tm[n]);
            }
}

// ---------------------------------------------------------------------------
// Kernel 2b: p/g-GEMM, FULL batch, 3 passes (f32-exact) -> f32 pbuf/gbuf.
// Grid (64 px-tiles, 16 b) = 1024 blocks; block = p128+g128 rows x 64 px.
// ---------------------------------------------------------------------------
__global__ __launch_bounds__(256, 4) void k_mm1(
    const u16* __restrict__ xThi, const u16* __restrict__ xTlo,
    const u16* __restrict__ pAhi, const u16* __restrict__ pAlo,
    float* __restrict__ pbuf, float* __restrict__ gbuf)
{
    __shared__ short8 BldsV[2048];           // 32 KB
    char* Blds = (char*)BldsV;
    int tid = threadIdx.x, lane = tid & 63, wid = tid >> 6;
    int rt  = 2 + (wid >> 1);                // 2: p rows, 3: g rows
    int mbb = (wid & 1) * 4;
    int pix0 = blockIdx.x * 64;
    int bg   = blockIdx.y;

    const char* srcHi = (const char*)(xThi + ((size_t)bg * 4096 + pix0) * 256);
    const char* srcLo = (const char*)(xTlo + ((size_t)bg * 4096 + pix0) * 256);
    const char* aHi = (const char*)pAhi + rt * 65536 + mbb * 1024 + lane * 16;
    const char* aLo = (const char*)pAlo + rt * 65536 + mbb * 1024 + lane * 16;

    f32x4 acc[4][4];
    #pragma unroll
    for (int m = 0; m < 4; ++m)
        #pragma unroll
        for (int n = 0; n < 4; ++n) acc[m][n] = (f32x4)0.0f;

    STAGE8(srcHi);
    __syncthreads();
    MFMA_PASS(aHi);
    MFMA_PASS(aLo);
    __syncthreads();     // all waves done reading hi panel
    STAGE8(srcLo);
    __syncthreads();
    MFMA_PASS(aHi);

    float* dst = (wid < 2) ? pbuf : gbuf;
    #pragma unroll
    for (int m = 0; m < 4; ++m)
        #pragma unroll
        for (int n = 0; n < 4; ++n)
            #pragma unroll
            for (int r = 0; r < 4; ++r) {
                int row = (wid & 1) * 64 + m * 16 + (lane >> 4) * 4 + r;  // 0..127
                int col = pix0 + n * 16 + (lane & 15);
                dst[((size_t)bg * 128 + row) * 4096 + col] = acc[m][n][r];
            }
}

// ---------------------------------------------------------------------------
// Kernel 3: attention dot (f32), FULL batch.  Block per (c, gi, b).
// ---------------------------------------------------------------------------
__global__ __launch_bounds__(256) void k_att(
    const float* __restrict__ pbuf, const float* __restrict__ gbuf,
    float* __restrict__ att)
{
    __shared__ float plds[HW_];
    __shared__ float glds[HW_];
    __shared__ float scr[8];
    int c  = blockIdx.x;   // 0..31
    int gi = blockIdx.y;   // 0..3
    int b  = blockIdx.z;   // 0..15
    int tid = threadIdx.x;

    const float* pp = pbuf + ((size_t)b * 128 + gi * 32 + c) * HW_;
    const float* gg = gbuf + ((size_t)b * 128 + gi * 32 + c) * HW_;

    float racc = 0.0f;
    #pragma unroll
    for (int it = 0; it < 4; ++it) {
        int i = it * 1024 + tid * 4;
        float4 pv = *(const float4*)(pp + i);
        float4 gv = *(const float4*)(gg + i);
        *(float4*)(&plds[i]) = pv;
        *(float4*)(&glds[i]) = gv;
        racc += pv.x * gv.x + pv.y * gv.y + pv.z * gv.z + pv.w * gv.w;
    }
    __syncthreads();

    float pacc = 0.0f;
    #pragma unroll 4
    for (int i = tid; i < HW_; i += 256) {
        int h = i >> 6, w = i & 63;
        int h0 = max(h - 1, 0), h1 = min(h + 1, 63);
        int w0 = max(w - 1, 0), w1 = min(w + 1, 63);
        float mp = -3.0e38f, mg = -3.0e38f;
        for (int hh = h0; hh <= h1; ++hh)
            for (int ww = w0; ww <= w1; ++ww) {
                mp = fmaxf(mp, plds[hh * 64 + ww]);
                mg = fmaxf(mg, glds[hh * 64 + ww]);
            }
        pacc += mp * mg;
    }

    #pragma unroll
    for (int off = 32; off > 0; off >>= 1) {
        racc += __shfl_down(racc, off, 64);
        pacc += __shfl_down(pacc, off, 64);
    }
    int lane = tid & 63, wid = tid >> 6;
    if (lane == 0) { scr[wid] = racc; scr[4 + wid] = pacc; }
    __syncthreads();
    if (tid == 0) {
        atomicAdd(&att[b * 8 + gi],     scr[0] + scr[1] + scr[2] + scr[3]);
        atomicAdd(&att[b * 8 + gi + 4], scr[4] + scr[5] + scr[6] + scr[7]);
    }
}

// ---------------------------------------------------------------------------
// Kernel 4: per-row softmax stats (bf16 input).  rowstat = (max, 1/expsum)
// ---------------------------------------------------------------------------
__global__ __launch_bounds__(256) void k_smax(
    const u16* __restrict__ tbuf, float2* __restrict__ rowstat)
{
    __shared__ float scr[8];
    int r = blockIdx.x;
    const u16* tr = tbuf + (size_t)r * HW_;
    int tid = threadIdx.x;
    int lane = tid & 63, wid = tid >> 6;

    float vals[16];
    float mx = -3.0e38f;
    #pragma unroll
    for (int it = 0; it < 2; ++it) {
        short8 v = *(const short8*)(tr + it * 2048 + tid * 8);
        #pragma unroll
        for (int j = 0; j < 8; ++j) {
            float f = bf2f((u16)v[j]);
            vals[it * 8 + j] = f;
            mx = fmaxf(mx, f);
        }
    }
    #pragma unroll
    for (int off = 32; off > 0; off >>= 1) mx = fmaxf(mx, __shfl_down(mx, off, 64));
    if (lane == 0) scr[wid] = mx;
    __syncthreads();
    if (tid == 0) scr[0] = fmaxf(fmaxf(scr[0], scr[1]), fmaxf(scr[2], scr[3]));
    __syncthreads();
    float m = scr[0];
    __syncthreads();

    float s = 0.0f;
    #pragma unroll
    for (int j = 0; j < 16; ++j) s += __expf(vals[j] - m);
    #pragma unroll
    for (int off = 32; off > 0; off >>= 1) s += __shfl_down(s, off, 64);
    if (lane == 0) scr[4 + wid] = s;
    __syncthreads();
    if (tid == 0) {
        float S = scr[4] + scr[5] + scr[6] + scr[7];
        rowstat[r] = make_float2(m, 1.0f / S);
    }
}

// ---------------------------------------------------------------------------
// Kernel 5: fused softmax-apply + xz mix + GN stats, in place over bf16 tbuf.
// Block per (pt 512px, gi, b); 2 px per thread; wz in 4 KB LDS.
// ---------------------------------------------------------------------------
__global__ __launch_bounds__(256) void k_xz2(
    u16* __restrict__ tbuf, const float* __restrict__ Wz,
    const float2* __restrict__ rowstat, const float* __restrict__ att,
    float* __restrict__ stats)
{
    __shared__ float wz[32][32];
    __shared__ float2 rs[32];
    __shared__ float scr[8];
    int pt  = blockIdx.x;   // 0..7  (512-pixel tile)
    int gi  = blockIdx.y;   // 0..7
    int b   = blockIdx.z;   // 0..15
    int tid = threadIdx.x;
    int px  = pt * 512 + tid * 2;

    const float* wzg = Wz + gi * 1024;
    #pragma unroll
    for (int i = 0; i < 4; ++i) {
        int idx = tid + i * 256;
        wz[idx >> 5][idx & 31] = wzg[idx];
    }
    if (tid < 32) rs[tid] = rowstat[b * 256 + gi * 32 + tid];
    __syncthreads();

    u16* base = tbuf + ((size_t)b * 256 + gi * 32) * HW_;
    float2 v[32];
    #pragma unroll
    for (int i = 0; i < 32; ++i) {
        unsigned rv = *(const unsigned*)(base + (size_t)i * HW_ + px);
        float m = rs[i].x, inv = rs[i].y;
        v[i].x = __expf(bf2f((u16)(rv & 0xffffu)) - m) * inv;
        v[i].y = __expf(bf2f((u16)(rv >> 16)) - m) * inv;
    }

    float a = att[b * 8 + gi];
    float s1 = 0.0f, s2 = 0.0f;
    #pragma unroll
    for (int o = 0; o < 32; ++o) {
        const float4* wzo = (const float4*)(&wz[o][0]);
        float ax = 0.0f, ay = 0.0f;
        #pragma unroll
        for (int j = 0; j < 8; ++j) {
            float4 w = wzo[j];
            ax = fmaf(w.x, v[4*j+0].x, ax); ay = fmaf(w.x, v[4*j+0].y, ay);
            ax = fmaf(w.y, v[4*j+1].x, ax); ay = fmaf(w.y, v[4*j+1].y, ay);
            ax = fmaf(w.z, v[4*j+2].x, ax); ay = fmaf(w.z, v[4*j+2].y, ay);
            ax = fmaf(w.w, v[4*j+3].x, ax); ay = fmaf(w.w, v[4*j+3].y, ay);
        }
        ax *= a; ay *= a;
        unsigned ov = (unsigned)f2bf(ax) | ((unsigned)f2bf(ay) << 16);
        *(unsigned*)(base + (size_t)o * HW_ + px) = ov;
        s1 += ax + ay;
        s2 = fmaf(ax, ax, fmaf(ay, ay, s2));
    }

    #pragma unroll
    for (int off = 32; off > 0; off >>= 1) {
        s1 += __shfl_down(s1, off, 64);
        s2 += __shfl_down(s2, off, 64);
    }
    int lane = tid & 63, wid = tid >> 6;
    if (lane == 0) { scr[wid] = s1; scr[4 + wid] = s2; }
    __syncthreads();
    if (tid == 0) {
        atomicAdd(&stats[(b * 8 + gi) * 2 + 0], scr[0] + scr[1] + scr[2] + scr[3]);
        atomicAdd(&stats[(b * 8 + gi) * 2 + 1], scr[4] + scr[5] + scr[6] + scr[7]);
    }
}

// ---------------------------------------------------------------------------
// Kernel 6: GroupNorm finalize + affine + residual (4 elems/thread)
// ---------------------------------------------------------------------------
__global__ __launch_bounds__(256) void k_finalize(
    const u16* __restrict__ xzbuf, const float* __restrict__ x,
    const float* __restrict__ stats, const float* __restrict__ gamma,
    const float* __restrict__ beta, float* __restrict__ out)
{
    size_t i0 = ((size_t)blockIdx.x * 256 + threadIdx.x) * 4;
    int c  = (int)((i0 >> 12) & 255);
    int bg = (int)(i0 >> 17);
    float s1 = stats[bg * 2], s2 = stats[bg * 2 + 1];
    const float invN = 1.0f / 131072.0f;
    float mu  = s1 * invN;
    float var = s2 * invN - mu * mu;
    float rs  = rsqrtf(var + EPSV);
    float ga = gamma[c], be = beta[c];

    union { unsigned long long u; u16 h[4]; } vv;
    vv.u = *(const unsigned long long*)(xzbuf + i0);
    float4 xv = *(const float4*)(x + i0);
    float4 o;
    o.x = (bf2f(vv.h[0]) - mu) * rs * ga + be + xv.x;
    o.y = (bf2f(vv.h[1]) - mu) * rs * ga + be + xv.y;
    o.z = (bf2f(vv.h[2]) - mu) * rs * ga + be + xv.z;
    o.w = (bf2f(vv.h[3]) - mu) * rs * ga + be + xv.w;
    *(float4*)(out + i0) = o;
}

// ---------------------------------------------------------------------------
extern "C" void kernel_launch(void* const* d_in, const int* in_sizes, int n_in,
                              void* d_out, int out_size, void* d_ws, size_t ws_size,
                              hipStream_t stream)
{
    const float* x     = (const float*)d_in[0];
    const float* mask  = (const float*)d_in[1];
    const float* Wt    = (const float*)d_in[2];
    const float* Wtm   = (const float*)d_in[3];
    const float* Wp    = (const float*)d_in[4];
    const float* Wg    = (const float*)d_in[5];
    const float* Wz    = (const float*)d_in[6];
    const float* gamma = (const float*)d_in[7];
    const float* beta  = (const float*)d_in[8];
    float* out = (float*)d_out;

    // workspace layout (bytes), total ~235.7 MB (ws_size = 256 MiB):
    //   tbuf  (bf16, full batch): 33,554,432   (t -> xz in place)
    //   xThi / xTlo (bf16, full batch): 33,554,432 each
    //   pbuf / gbuf (f32, full batch): 67,108,864 each
    //   pAhi/pAlo: 262,144 each ; tmod (f32): 262,144
    //   att/stats: 1,536 ; rowstat (float2[4096]): 32,768
    char* ws = (char*)d_ws;
    u16*   tbuf  = (u16*)(ws);
    u16*   xThi  = (u16*)(ws + 33554432);
    u16*   xTlo  = (u16*)(ws + 67108864);
    float* pbuf  = (float*)(ws + 100663296);
    float* gbuf  = (float*)(ws + 167772160);
    u16*   pAhi  = (u16*)(ws + 234881024);
    u16*   pAlo  = (u16*)(ws + 235143168);
    float* tmod  = (float*)(ws + 235405312);
    float* att   = (float*)(ws + 235667456);
    float* stats = att + 128;
    float2* rowstat = (float2*)(ws + 235669504);

    k_packA    <<<64, 256, 0, stream>>>(Wt, Wp, Wg, pAhi, pAlo);
    k_tmod_zero<<<256, 256, 0, stream>>>(mask, Wtm, tmod, att, stats);
    k_transpose<<<dim3(32, 8, 16), 256, 0, stream>>>(x, xThi, xTlo);
    k_mm0      <<<dim3(64, 16), 256, 0, stream>>>(xThi, pAhi, tmod, tbuf);
    k_mm1      <<<dim3(64, 16), 256, 0, stream>>>(xThi, xTlo, pAhi, pAlo, pbuf, gbuf);
    k_att      <<<dim3(32, 4, 16), 256, 0, stream>>>(pbuf, gbuf, att);
    k_smax     <<<4096, 256, 0, stream>>>(tbuf, rowstat);
    k_xz2      <<<dim3(8, 8, 16), 256, 0, stream>>>(tbuf, Wz, rowstat, att, stats);
    k_finalize <<<16384, 256, 0, stream>>>(tbuf, x, stats, gamma, beta, out);
}

// Round 12
// 277.890 us; speedup vs baseline: 1.0658x; 1.0658x over previous
//
#include <hip/hip_runtime.h>
#include <math.h>

#define B_      16
#define CIN     256
#define HW_     4096          // 64x64
#define PLANES  256
#define G_      8
#define EPSV    1e-5f

typedef unsigned short u16;
typedef __attribute__((ext_vector_type(8))) short short8;   // 8 bf16 (4 VGPRs)
typedef __attribute__((ext_vector_type(4))) float f32x4;    // MFMA acc

__device__ inline u16 f2bf(float f) {
    union { float f; unsigned u; } v; v.f = f;
    unsigned u = v.u;
    return (u16)((u + 0x7fffu + ((u >> 16) & 1u)) >> 16);   // RNE
}
__device__ inline float bf2f(u16 h) {
    union { unsigned u; float f; } v; v.u = ((unsigned)h) << 16;
    return v.f;
}

// ---------------------------------------------------------------------------
// Kernel 0a: pack Wt|Wp|Wg (512x256 f32) into MFMA A-fragment order, split
// into bf16 hi + lo (w = hi + lo, exact to ~2^-16 rel).
// slot (rt 0..3, kt 0..7, mb 0..7, lane 0..63, j 0..7):
//   row = rt*128 + mb*16 + (lane&15); k = kt*32 + (lane>>4)*8 + j
// ---------------------------------------------------------------------------
__global__ __launch_bounds__(256) void k_packA(
    const float* __restrict__ Wt, const float* __restrict__ Wp,
    const float* __restrict__ Wg,
    u16* __restrict__ pAhi, u16* __restrict__ pAlo)
{
    int t = blockIdx.x * 256 + threadIdx.x;      // 0..16383
    int lane = t & 63;
    int mb   = (t >> 6) & 7;
    int kt   = (t >> 9) & 7;
    int rt   = (t >> 12) & 3;
    int row = rt * 128 + mb * 16 + (lane & 15);
    int k0  = kt * 32 + (lane >> 4) * 8;
    const float* src;
    if      (row < 256) src = Wt + (size_t)row * 256;
    else if (row < 384) src = Wp + (size_t)(row - 256) * 256;
    else                src = Wg + (size_t)(row - 384) * 256;
    u16 hv[8], lv[8];
    #pragma unroll
    for (int j = 0; j < 8; ++j) {
        float w = src[k0 + j];
        u16 h = f2bf(w);
        hv[j] = h;
        lv[j] = f2bf(w - bf2f(h));
    }
    *(short8*)(pAhi + (size_t)t * 8) = *(short8*)hv;
    *(short8*)(pAlo + (size_t)t * 8) = *(short8*)lv;
}

// ---------------------------------------------------------------------------
// Kernel 0b: transpose x[b][256][4096] f32 -> xThi/xTlo[b][4096][256]
// bf16 hi/lo split.  FULL batch, one launch (4096 blocks).
// ---------------------------------------------------------------------------
__global__ __launch_bounds__(256) void k_transpose(
    const float* __restrict__ x, u16* __restrict__ xThi,
    u16* __restrict__ xTlo)
{
    __shared__ float tile[32][129];
    int tid = threadIdx.x;
    int px0 = blockIdx.x * 128;
    int c0  = blockIdx.y * 32;
    int bg  = blockIdx.z;

    #pragma unroll
    for (int it = 0; it < 16; ++it) {
        int flat = it * 256 + tid;
        int c_l = flat >> 7, p_l = flat & 127;
        tile[c_l][p_l] = x[((size_t)bg * 256 + c0 + c_l) * 4096 + px0 + p_l];
    }
    __syncthreads();
    #pragma unroll
    for (int it = 0; it < 8; ++it) {
        int flat = it * 256 + tid;          // 0..2047
        int p_l = flat >> 4;
        int c_l = (flat & 15) * 2;
        float v0 = tile[c_l][p_l], v1 = tile[c_l + 1][p_l];
        u16 h0 = f2bf(v0), h1 = f2bf(v1);
        u16 l0 = f2bf(v0 - bf2f(h0)), l1 = f2bf(v1 - bf2f(h1));
        size_t o = ((size_t)bg * 4096 + px0 + p_l) * 256 + c0 + c_l;
        u16 ho[2] = { h0, h1 };
        u16 lo[2] = { l0, l1 };
        *(unsigned*)(xThi + o) = *(unsigned*)ho;
        *(unsigned*)(xTlo + o) = *(unsigned*)lo;
    }
}

// ---------------------------------------------------------------------------
// Kernel 1: tmod + zero att/stats
// ---------------------------------------------------------------------------
__global__ __launch_bounds__(256) void k_tmod_zero(
    const float* __restrict__ mask, const float* __restrict__ Wtm,
    float* __restrict__ tmod, float* __restrict__ att, float* __restrict__ stats)
{
    int idx = blockIdx.x * 256 + threadIdx.x;
    float w0 = Wtm[0], w1 = Wtm[1];
    if (idx < B_ * HW_) {
        int b = idx >> 12, pix = idx & 4095;
        const float* mb = mask + (size_t)b * 2 * HW_;
        tmod[idx] = 1.0f + w0 * mb[pix] + w1 * mb[HW_ + pix];
    }
    if (blockIdx.x == 0) {
        if (threadIdx.x < 128) att[threadIdx.x] = 0.0f;
        stats[threadIdx.x] = 0.0f;
    }
}

// ---------------------------------------------------------------------------
// Merged GEMM kernel.  Block: 64 px (one image row), ALL 512 output rows,
// 4 waves.  32 KB LDS B-panel (XOR-swizzled), staged hi then re-staged lo.
// Phases:  t-pass (1x MFMA, bf16)  -> bf16 tbuf (* tmod)
//          p/g hi (Whi*xhi + Wlo*xhi), lo (Whi*xlo)  -> f32 pbuf/gbuf exact
// __launch_bounds__(256,3): cap ~170 VGPR (R10 measured 176 natural; shave,
// don't spill) -> 3 blocks/CU, 12 waves/CU.
// ---------------------------------------------------------------------------
#define STAGE8(SRC)                                                           \
    _Pragma("unroll")                                                         \
    for (int it = 0; it < 8; ++it) {                                          \
        int cidx = it * 256 + tid;                                            \
        int px   = cidx >> 5;                                                 \
        int boff = (cidx & 31) << 4;                                          \
        short8 v = *(const short8*)((SRC) + (size_t)px * 512 + boff);         \
        *(short8*)(Blds + px * 512 + (boff ^ ((px & 7) << 4))) = v;           \
    }

#define MFMA_PASS(ABASE)                                                      \
    _Pragma("unroll")                                                         \
    for (int kt = 0; kt < 8; ++kt) {                                          \
        short8 a[4], bb[4];                                                   \
        _Pragma("unroll")                                                     \
        for (int m = 0; m < 4; ++m)                                           \
            a[m] = *(const short8*)((ABASE) + kt * 8192 + m * 1024);          \
        int off = ((kt * 64) + ((lane >> 4) << 4)) ^ ((lane & 7) << 4);       \
        _Pragma("unroll")                                                     \
        for (int n = 0; n < 4; ++n) {                                         \
            int px = n * 16 + (lane & 15);                                    \
            bb[n] = *(const short8*)(Blds + px * 512 + off);                  \
        }                                                                     \
        _Pragma("unroll")                                                     \
        for (int m = 0; m < 4; ++m)                                           \
            _Pragma("unroll")                                                 \
            for (int n = 0; n < 4; ++n)                                       \
                acc[m][n] = __builtin_amdgcn_mfma_f32_16x16x32_bf16(          \
                    a[m], bb[n], acc[m][n], 0, 0, 0);                         \
    }

__global__ __launch_bounds__(256, 3) void k_mmf(
    const u16* __restrict__ xThi, const u16* __restrict__ xTlo,
    const u16* __restrict__ pAhi, const u16* __restrict__ pAlo,
    const float* __restrict__ tmod, u16* __restrict__ tbuf,
    float* __restrict__ pbuf, float* __restrict__ gbuf)
{
    __shared__ short8 BldsV[2048];           // 32 KB
    char* Blds = (char*)BldsV;
    int tid = threadIdx.x, lane = tid & 63, wid = tid >> 6;
    int mbb = (wid & 1) * 4;
    int pix0 = blockIdx.x * 64;
    int bg   = blockIdx.y;

    const char* srcHi = (const char*)(xThi + ((size_t)bg * 4096 + pix0) * 256);
    const char* srcLo = (const char*)(xTlo + ((size_t)bg * 4096 + pix0) * 256);
    // A bases: t rows use rt = wid>>1 (0..1); p/g rows use rt = 2 + (wid>>1)
    const char* aHiT = (const char*)pAhi + (wid >> 1) * 65536 + mbb * 1024 + lane * 16;
    const char* aHiP = aHiT + 2 * 65536;
    const char* aLoP = (const char*)pAlo + (2 + (wid >> 1)) * 65536 + mbb * 1024 + lane * 16;

    f32x4 acc[4][4];

    // ---- stage hi panel ----
    STAGE8(srcHi);
    __syncthreads();

    // ---- t pass (bf16-level) ----
    #pragma unroll
    for (int m = 0; m < 4; ++m)
        #pragma unroll
        for (int n = 0; n < 4; ++n) acc[m][n] = (f32x4)0.0f;
    MFMA_PASS(aHiT);

    // t epilogue (acc dead after this -> registers reused for p/g)
    {
        float tm[4];
        #pragma unroll
        for (int n = 0; n < 4; ++n) tm[n] = tmod[bg * 4096 + pix0 + n * 16 + (lane & 15)];
        #pragma unroll
        for (int m = 0; m < 4; ++m)
            #pragma unroll
            for (int n = 0; n < 4; ++n)
                #pragma unroll
                for (int r = 0; r < 4; ++r) {
                    int row = wid * 64 + m * 16 + (lane >> 4) * 4 + r;   // 0..255
                    int col = pix0 + n * 16 + (lane & 15);
                    tbuf[((size_t)bg * 256 + row) * 4096 + col] = f2bf(acc[m][n][r] * tm[n]);
                }
    }

    // ---- p/g: Whi*xhi + Wlo*xhi on the hi panel ----
    #pragma unroll
    for (int m = 0; m < 4; ++m)
        #pragma unroll
        for (int n = 0; n < 4; ++n) acc[m][n] = (f32x4)0.0f;
    MFMA_PASS(aHiP);
    MFMA_PASS(aLoP);

    __syncthreads();     // all waves done reading hi panel
    STAGE8(srcLo);
    __syncthreads();

    // ---- p/g: + Whi*xlo ----
    MFMA_PASS(aHiP);

    float* dst = (wid < 2) ? pbuf : gbuf;
    #pragma unroll
    for (int m = 0; m < 4; ++m)
        #pragma unroll
        for (int n = 0; n < 4; ++n)
            #pragma unroll
            for (int r = 0; r < 4; ++r) {
                int row = (wid & 1) * 64 + m * 16 + (lane >> 4) * 4 + r;  // 0..127
                int col = pix0 + n * 16 + (lane & 15);
                dst[((size_t)bg * 128 + row) * 4096 + col] = acc[m][n][r];
            }
}

// ---------------------------------------------------------------------------
// Kernel 3: attention dot (f32), FULL batch.  Block per (c, gi, b).
// ---------------------------------------------------------------------------
__global__ __launch_bounds__(256) void k_att(
    const float* __restrict__ pbuf, const float* __restrict__ gbuf,
    float* __restrict__ att)
{
    __shared__ float plds[HW_];
    __shared__ float glds[HW_];
    __shared__ float scr[8];
    int c  = blockIdx.x;   // 0..31
    int gi = blockIdx.y;   // 0..3
    int b  = blockIdx.z;   // 0..15
    int tid = threadIdx.x;

    const float* pp = pbuf + ((size_t)b * 128 + gi * 32 + c) * HW_;
    const float* gg = gbuf + ((size_t)b * 128 + gi * 32 + c) * HW_;

    float racc = 0.0f;
    #pragma unroll
    for (int it = 0; it < 4; ++it) {
        int i = it * 1024 + tid * 4;
        float4 pv = *(const float4*)(pp + i);
        float4 gv = *(const float4*)(gg + i);
        *(float4*)(&plds[i]) = pv;
        *(float4*)(&glds[i]) = gv;
        racc += pv.x * gv.x + pv.y * gv.y + pv.z * gv.z + pv.w * gv.w;
    }
    __syncthreads();

    float pacc = 0.0f;
    #pragma unroll 4
    for (int i = tid; i < HW_; i += 256) {
        int h = i >> 6, w = i & 63;
        int h0 = max(h - 1, 0), h1 = min(h + 1, 63);
        int w0 = max(w - 1, 0), w1 = min(w + 1, 63);
        float mp = -3.0e38f, mg = -3.0e38f;
        for (int hh = h0; hh <= h1; ++hh)
            for (int ww = w0; ww <= w1; ++ww) {
                mp = fmaxf(mp, plds[hh * 64 + ww]);
                mg = fmaxf(mg, glds[hh * 64 + ww]);
            }
        pacc += mp * mg;
    }

    #pragma unroll
    for (int off = 32; off > 0; off >>= 1) {
        racc += __shfl_down(racc, off, 64);
        pacc += __shfl_down(pacc, off, 64);
    }
    int lane = tid & 63, wid = tid >> 6;
    if (lane == 0) { scr[wid] = racc; scr[4 + wid] = pacc; }
    __syncthreads();
    if (tid == 0) {
        atomicAdd(&att[b * 8 + gi],     scr[0] + scr[1] + scr[2] + scr[3]);
        atomicAdd(&att[b * 8 + gi + 4], scr[4] + scr[5] + scr[6] + scr[7]);
    }
}

// ---------------------------------------------------------------------------
// Kernel 4: per-row softmax stats (bf16 input).  rowstat = (max, 1/expsum)
// ---------------------------------------------------------------------------
__global__ __launch_bounds__(256) void k_smax(
    const u16* __restrict__ tbuf, float2* __restrict__ rowstat)
{
    __shared__ float scr[8];
    int r = blockIdx.x;
    const u16* tr = tbuf + (size_t)r * HW_;
    int tid = threadIdx.x;
    int lane = tid & 63, wid = tid >> 6;

    float vals[16];
    float mx = -3.0e38f;
    #pragma unroll
    for (int it = 0; it < 2; ++it) {
        short8 v = *(const short8*)(tr + it * 2048 + tid * 8);
        #pragma unroll
        for (int j = 0; j < 8; ++j) {
            float f = bf2f((u16)v[j]);
            vals[it * 8 + j] = f;
            mx = fmaxf(mx, f);
        }
    }
    #pragma unroll
    for (int off = 32; off > 0; off >>= 1) mx = fmaxf(mx, __shfl_down(mx, off, 64));
    if (lane == 0) scr[wid] = mx;
    __syncthreads();
    if (tid == 0) scr[0] = fmaxf(fmaxf(scr[0], scr[1]), fmaxf(scr[2], scr[3]));
    __syncthreads();
    float m = scr[0];
    __syncthreads();

    float s = 0.0f;
    #pragma unroll
    for (int j = 0; j < 16; ++j) s += __expf(vals[j] - m);
    #pragma unroll
    for (int off = 32; off > 0; off >>= 1) s += __shfl_down(s, off, 64);
    if (lane == 0) scr[4 + wid] = s;
    __syncthreads();
    if (tid == 0) {
        float S = scr[4] + scr[5] + scr[6] + scr[7];
        rowstat[r] = make_float2(m, 1.0f / S);
    }
}

// ---------------------------------------------------------------------------
// Kernel 5: fused softmax-apply + xz mix + GN stats, in place over bf16 tbuf.
// Block per (pt 512px, gi, b); 2 px per thread; wz in 4 KB LDS.
// ---------------------------------------------------------------------------
__global__ __launch_bounds__(256) void k_xz2(
    u16* __restrict__ tbuf, const float* __restrict__ Wz,
    const float2* __restrict__ rowstat, const float* __restrict__ att,
    float* __restrict__ stats)
{
    __shared__ float wz[32][32];
    __shared__ float2 rs[32];
    __shared__ float scr[8];
    int pt  = blockIdx.x;   // 0..7  (512-pixel tile)
    int gi  = blockIdx.y;   // 0..7
    int b   = blockIdx.z;   // 0..15
    int tid = threadIdx.x;
    int px  = pt * 512 + tid * 2;

    const float* wzg = Wz + gi * 1024;
    #pragma unroll
    for (int i = 0; i < 4; ++i) {
        int idx = tid + i * 256;
        wz[idx >> 5][idx & 31] = wzg[idx];
    }
    if (tid < 32) rs[tid] = rowstat[b * 256 + gi * 32 + tid];
    __syncthreads();

    u16* base = tbuf + ((size_t)b * 256 + gi * 32) * HW_;
    float2 v[32];
    #pragma unroll
    for (int i = 0; i < 32; ++i) {
        unsigned rv = *(const unsigned*)(base + (size_t)i * HW_ + px);
        float m = rs[i].x, inv = rs[i].y;
        v[i].x = __expf(bf2f((u16)(rv & 0xffffu)) - m) * inv;
        v[i].y = __expf(bf2f((u16)(rv >> 16)) - m) * inv;
    }

    float a = att[b * 8 + gi];
    float s1 = 0.0f, s2 = 0.0f;
    #pragma unroll
    for (int o = 0; o < 32; ++o) {
        const float4* wzo = (const float4*)(&wz[o][0]);
        float ax = 0.0f, ay = 0.0f;
        #pragma unroll
        for (int j = 0; j < 8; ++j) {
            float4 w = wzo[j];
            ax = fmaf(w.x, v[4*j+0].x, ax); ay = fmaf(w.x, v[4*j+0].y, ay);
            ax = fmaf(w.y, v[4*j+1].x, ax); ay = fmaf(w.y, v[4*j+1].y, ay);
            ax = fmaf(w.z, v[4*j+2].x, ax); ay = fmaf(w.z, v[4*j+2].y, ay);
            ax = fmaf(w.w, v[4*j+3].x, ax); ay = fmaf(w.w, v[4*j+3].y, ay);
        }
        ax *= a; ay *= a;
        unsigned ov = (unsigned)f2bf(ax) | ((unsigned)f2bf(ay) << 16);
        *(unsigned*)(base + (size_t)o * HW_ + px) = ov;
        s1 += ax + ay;
        s2 = fmaf(ax, ax, fmaf(ay, ay, s2));
    }

    #pragma unroll
    for (int off = 32; off > 0; off >>= 1) {
        s1 += __shfl_down(s1, off, 64);
        s2 += __shfl_down(s2, off, 64);
    }
    int lane = tid & 63, wid = tid >> 6;
    if (lane == 0) { scr[wid] = s1; scr[4 + wid] = s2; }
    __syncthreads();
    if (tid == 0) {
        atomicAdd(&stats[(b * 8 + gi) * 2 + 0], scr[0] + scr[1] + scr[2] + scr[3]);
        atomicAdd(&stats[(b * 8 + gi) * 2 + 1], scr[4] + scr[5] + scr[6] + scr[7]);
    }
}

// ---------------------------------------------------------------------------
// Kernel 6: GroupNorm finalize + affine + residual (4 elems/thread)
// ---------------------------------------------------------------------------
__global__ __launch_bounds__(256) void k_finalize(
    const u16* __restrict__ xzbuf, const float* __restrict__ x,
    const float* __restrict__ stats, const float* __restrict__ gamma,
    const float* __restrict__ beta, float* __restrict__ out)
{
    size_t i0 = ((size_t)blockIdx.x * 256 + threadIdx.x) * 4;
    int c  = (int)((i0 >> 12) & 255);
    int bg = (int)(i0 >> 17);
    float s1 = stats[bg * 2], s2 = stats[bg * 2 + 1];
    const float invN = 1.0f / 131072.0f;
    float mu  = s1 * invN;
    float var = s2 * invN - mu * mu;
    float rs  = rsqrtf(var + EPSV);
    float ga = gamma[c], be = beta[c];

    union { unsigned long long u; u16 h[4]; } vv;
    vv.u = *(const unsigned long long*)(xzbuf + i0);
    float4 xv = *(const float4*)(x + i0);
    float4 o;
    o.x = (bf2f(vv.h[0]) - mu) * rs * ga + be + xv.x;
    o.y = (bf2f(vv.h[1]) - mu) * rs * ga + be + xv.y;
    o.z = (bf2f(vv.h[2]) - mu) * rs * ga + be + xv.z;
    o.w = (bf2f(vv.h[3]) - mu) * rs * ga + be + xv.w;
    *(float4*)(out + i0) = o;
}

// ---------------------------------------------------------------------------
extern "C" void kernel_launch(void* const* d_in, const int* in_sizes, int n_in,
                              void* d_out, int out_size, void* d_ws, size_t ws_size,
                              hipStream_t stream)
{
    const float* x     = (const float*)d_in[0];
    const float* mask  = (const float*)d_in[1];
    const float* Wt    = (const float*)d_in[2];
    const float* Wtm   = (const float*)d_in[3];
    const float* Wp    = (const float*)d_in[4];
    const float* Wg    = (const float*)d_in[5];
    const float* Wz    = (const float*)d_in[6];
    const float* gamma = (const float*)d_in[7];
    const float* beta  = (const float*)d_in[8];
    float* out = (float*)d_out;

    // workspace layout (bytes), ws_size = 256 MiB:
    //   tbuf  (bf16, full batch): 33,554,432   (t -> xz in place)
    //   xThi / xTlo (bf16, full batch): 33,554,432 each
    //   pbuf / gbuf (f32, full batch, 33.5 MB used each; 67 MB slots)
    //   pAhi/pAlo: 262,144 each ; tmod (f32): 262,144
    //   att/stats: 1,536 ; rowstat (float2[4096]): 32,768
    char* ws = (char*)d_ws;
    u16*   tbuf  = (u16*)(ws);
    u16*   xThi  = (u16*)(ws + 33554432);
    u16*   xTlo  = (u16*)(ws + 67108864);
    float* pbuf  = (float*)(ws + 100663296);
    float* gbuf  = (float*)(ws + 167772160);
    u16*   pAhi  = (u16*)(ws + 234881024);
    u16*   pAlo  = (u16*)(ws + 235143168);
    float* tmod  = (float*)(ws + 235405312);
    float* att   = (float*)(ws + 235667456);
    float* stats = att + 128;
    float2* rowstat = (float2*)(ws + 235669504);

    k_packA    <<<64, 256, 0, stream>>>(Wt, Wp, Wg, pAhi, pAlo);
    k_tmod_zero<<<256, 256, 0, stream>>>(mask, Wtm, tmod, att, stats);
    k_transpose<<<dim3(32, 8, 16), 256, 0, stream>>>(x, xThi, xTlo);
    k_mmf      <<<dim3(64, 16), 256, 0, stream>>>(xThi, xTlo, pAhi, pAlo, tmod,
                                                  tbuf, pbuf, gbuf);
    k_att      <<<dim3(32, 4, 16), 256, 0, stream>>>(pbuf, gbuf, att);
    k_smax     <<<4096, 256, 0, stream>>>(tbuf, rowstat);
    k_xz2      <<<dim3(8, 8, 16), 256, 0, stream>>>(tbuf, Wz, rowstat, att, stats);
    k_finalize <<<16384, 256, 0, stream>>>(tbuf, x, stats, gamma, beta, out);
}

// Round 13
// 195.800 us; speedup vs baseline: 1.5127x; 1.4193x over previous
//
#include <hip/hip_runtime.h>
#include <math.h>

#define B_      16
#define CIN     256
#define HW_     4096          // 64x64
#define PLANES  256
#define G_      8
#define EPSV    1e-5f

typedef unsigned short u16;
typedef __attribute__((ext_vector_type(8))) short short8;   // 8 bf16 (4 VGPRs)
typedef __attribute__((ext_vector_type(4))) float f32x4;    // MFMA acc

__device__ inline u16 f2bf(float f) {
    union { float f; unsigned u; } v; v.f = f;
    unsigned u = v.u;
    return (u16)((u + 0x7fffu + ((u >> 16) & 1u)) >> 16);   // RNE
}
__device__ inline float bf2f(u16 h) {
    union { unsigned u; float f; } v; v.u = ((unsigned)h) << 16;
    return v.f;
}

// ---------------------------------------------------------------------------
// Kernel 0a: pack Wt|Wp|Wg (512x256 f32) into MFMA A-fragment order, split
// into bf16 hi + lo (w = hi + lo, exact to ~2^-16 rel).
// slot (rt 0..3, kt 0..7, mb 0..7, lane 0..63, j 0..7):
//   row = rt*128 + mb*16 + (lane&15); k = kt*32 + (lane>>4)*8 + j
// byte offset = rt*65536 + kt*8192 + mb*1024 + lane*16
// ---------------------------------------------------------------------------
__global__ __launch_bounds__(256) void k_packA(
    const float* __restrict__ Wt, const float* __restrict__ Wp,
    const float* __restrict__ Wg,
    u16* __restrict__ pAhi, u16* __restrict__ pAlo)
{
    int t = blockIdx.x * 256 + threadIdx.x;      // 0..16383
    int lane = t & 63;
    int mb   = (t >> 6) & 7;
    int kt   = (t >> 9) & 7;
    int rt   = (t >> 12) & 3;
    int row = rt * 128 + mb * 16 + (lane & 15);
    int k0  = kt * 32 + (lane >> 4) * 8;
    const float* src;
    if      (row < 256) src = Wt + (size_t)row * 256;
    else if (row < 384) src = Wp + (size_t)(row - 256) * 256;
    else                src = Wg + (size_t)(row - 384) * 256;
    u16 hv[8], lv[8];
    #pragma unroll
    for (int j = 0; j < 8; ++j) {
        float w = src[k0 + j];
        u16 h = f2bf(w);
        hv[j] = h;
        lv[j] = f2bf(w - bf2f(h));
    }
    *(short8*)(pAhi + (size_t)t * 8) = *(short8*)hv;
    *(short8*)(pAlo + (size_t)t * 8) = *(short8*)lv;
}

// ---------------------------------------------------------------------------
// Kernel 0b: transpose x[b][256][4096] f32 -> xThi/xTlo[b][4096][256]
// bf16 hi/lo split.  FULL batch, one launch (4096 blocks).
// ---------------------------------------------------------------------------
__global__ __launch_bounds__(256) void k_transpose(
    const float* __restrict__ x, u16* __restrict__ xThi,
    u16* __restrict__ xTlo)
{
    __shared__ float tile[32][129];
    int tid = threadIdx.x;
    int px0 = blockIdx.x * 128;
    int c0  = blockIdx.y * 32;
    int bg  = blockIdx.z;

    #pragma unroll
    for (int it = 0; it < 16; ++it) {
        int flat = it * 256 + tid;
        int c_l = flat >> 7, p_l = flat & 127;
        tile[c_l][p_l] = x[((size_t)bg * 256 + c0 + c_l) * 4096 + px0 + p_l];
    }
    __syncthreads();
    #pragma unroll
    for (int it = 0; it < 8; ++it) {
        int flat = it * 256 + tid;          // 0..2047
        int p_l = flat >> 4;
        int c_l = (flat & 15) * 2;
        float v0 = tile[c_l][p_l], v1 = tile[c_l + 1][p_l];
        u16 h0 = f2bf(v0), h1 = f2bf(v1);
        u16 l0 = f2bf(v0 - bf2f(h0)), l1 = f2bf(v1 - bf2f(h1));
        size_t o = ((size_t)bg * 4096 + px0 + p_l) * 256 + c0 + c_l;
        u16 ho[2] = { h0, h1 };
        u16 lo[2] = { l0, l1 };
        *(unsigned*)(xThi + o) = *(unsigned*)ho;
        *(unsigned*)(xTlo + o) = *(unsigned*)lo;
    }
}

// ---------------------------------------------------------------------------
// Kernel 1: tmod + zero att/stats
// ---------------------------------------------------------------------------
__global__ __launch_bounds__(256) void k_tmod_zero(
    const float* __restrict__ mask, const float* __restrict__ Wtm,
    float* __restrict__ tmod, float* __restrict__ att, float* __restrict__ stats)
{
    int idx = blockIdx.x * 256 + threadIdx.x;
    float w0 = Wtm[0], w1 = Wtm[1];
    if (idx < B_ * HW_) {
        int b = idx >> 12, pix = idx & 4095;
        const float* mb = mask + (size_t)b * 2 * HW_;
        tmod[idx] = 1.0f + w0 * mb[pix] + w1 * mb[HW_ + pix];
    }
    if (blockIdx.x == 0) {
        if (threadIdx.x < 128) att[threadIdx.x] = 0.0f;
        stats[threadIdx.x] = 0.0f;
    }
}

// ---------------------------------------------------------------------------
// Shared GEMM building blocks (R9 geometry: block = 128 rows x 128 px,
// 4 waves 2x2, 64 KB LDS B-panel XOR-swizzled, natural register allocation).
// A addressing: per-wave precomputed byte base; fragment (kt,m) at
// base + kt*8192 + m*1024 (compile-time offsets).
// ---------------------------------------------------------------------------
#define STAGE16(SRC)                                                          \
    _Pragma("unroll")                                                         \
    for (int it = 0; it < 16; ++it) {                                         \
        int cidx = it * 256 + tid;                                            \
        int px   = cidx >> 5;                                                 \
        int boff = (cidx & 31) << 4;                                          \
        short8 v = *(const short8*)((SRC) + (size_t)px * 512 + boff);         \
        *(short8*)(Blds + px * 512 + (boff ^ ((px & 7) << 4))) = v;           \
    }

#define MFMA_PASS(ABASE)                                                      \
    _Pragma("unroll")                                                         \
    for (int kt = 0; kt < 8; ++kt) {                                          \
        short8 a[4], bb[4];                                                   \
        _Pragma("unroll")                                                     \
        for (int m = 0; m < 4; ++m)                                           \
            a[m] = *(const short8*)((ABASE) + kt * 8192 + m * 1024);          \
        int off = ((kt * 64) + ((lane >> 4) << 4)) ^ ((lane & 7) << 4);       \
        _Pragma("unroll")                                                     \
        for (int n = 0; n < 4; ++n) {                                         \
            int px = wn * 64 + n * 16 + (lane & 15);                          \
            bb[n] = *(const short8*)(Blds + px * 512 + off);                  \
        }                                                                     \
        _Pragma("unroll")                                                     \
        for (int m = 0; m < 4; ++m)                                           \
            _Pragma("unroll")                                                 \
            for (int n = 0; n < 4; ++n)                                       \
                acc[m][n] = __builtin_amdgcn_mfma_f32_16x16x32_bf16(          \
                    a[m], bb[n], acc[m][n], 0, 0, 0);                         \
    }

// Interleaved double pass: Whi and Wlo against the SAME staged panel.
// Shares the bb LDS reads; 32 MFMAs per kt iteration.
#define MFMA_PASS2(AH, AL)                                                    \
    _Pragma("unroll")                                                         \
    for (int kt = 0; kt < 8; ++kt) {                                          \
        short8 ah[4], al[4], bb[4];                                           \
        _Pragma("unroll")                                                     \
        for (int m = 0; m < 4; ++m) {                                         \
            ah[m] = *(const short8*)((AH) + kt * 8192 + m * 1024);            \
            al[m] = *(const short8*)((AL) + kt * 8192 + m * 1024);            \
        }                                                                     \
        int off = ((kt * 64) + ((lane >> 4) << 4)) ^ ((lane & 7) << 4);       \
        _Pragma("unroll")                                                     \
        for (int n = 0; n < 4; ++n) {                                         \
            int px = wn * 64 + n * 16 + (lane & 15);                          \
            bb[n] = *(const short8*)(Blds + px * 512 + off);                  \
        }                                                                     \
        _Pragma("unroll")                                                     \
        for (int m = 0; m < 4; ++m)                                           \
            _Pragma("unroll")                                                 \
            for (int n = 0; n < 4; ++n) {                                     \
                acc[m][n] = __builtin_amdgcn_mfma_f32_16x16x32_bf16(          \
                    ah[m], bb[n], acc[m][n], 0, 0, 0);                        \
                acc[m][n] = __builtin_amdgcn_mfma_f32_16x16x32_bf16(          \
                    al[m], bb[n], acc[m][n], 0, 0, 0);                        \
            }                                                                 \
    }

// ---------------------------------------------------------------------------
// Kernel 2a: t-GEMM, FULL batch, 1 bf16 pass -> bf16 tbuf (* tmod).
// Grid (32 px-tiles, 2 row-tiles, 16 b) = 1024 blocks.
// ---------------------------------------------------------------------------
__global__ __launch_bounds__(256) void k_mm0(
    const u16* __restrict__ xThi, const u16* __restrict__ pAhi,
    const float* __restrict__ tmod, u16* __restrict__ tbuf)
{
    __shared__ short8 BldsV[4096];           // 64 KB
    char* Blds = (char*)BldsV;
    int tid = threadIdx.x, lane = tid & 63, wid = tid >> 6;
    int wm = wid >> 1, wn = wid & 1;
    int pix0 = blockIdx.x * 128;
    int rt   = blockIdx.y;                   // 0..1 (t rows)
    int bg   = blockIdx.z;

    const char* srcHi = (const char*)(xThi + ((size_t)bg * 4096 + pix0) * 256);
    const char* aHi = (const char*)pAhi + rt * 65536 + wm * 4096 + lane * 16;

    f32x4 acc[4][4];
    #pragma unroll
    for (int m = 0; m < 4; ++m)
        #pragma unroll
        for (int n = 0; n < 4; ++n) acc[m][n] = (f32x4)0.0f;

    STAGE16(srcHi);
    __syncthreads();
    MFMA_PASS(aHi);

    int colb = pix0 + wn * 64;
    int rowb = rt * 128 + wm * 64;
    float tm[4];
    #pragma unroll
    for (int n = 0; n < 4; ++n) tm[n] = tmod[bg * 4096 + colb + n * 16 + (lane & 15)];
    #pragma unroll
    for (int m = 0; m < 4; ++m)
        #pragma unroll
        for (int n = 0; n < 4; ++n)
            #pragma unroll
            for (int r = 0; r < 4; ++r) {
                int row = rowb + m * 16 + (lane >> 4) * 4 + r;
                int col = colb + n * 16 + (lane & 15);
                tbuf[((size_t)bg * 256 + row) * 4096 + col] = f2bf(acc[m][n][r] * tm[n]);
            }
}

// ---------------------------------------------------------------------------
// Kernel 2b: p/g-GEMM, FULL batch, f32-exact -> f32 pbuf/gbuf.
// Phase 1: interleaved (Whi + Wlo) x xhi (shared B reads, 32 MFMA/kt).
// Phase 2: restage lo panel, + Whi x xlo.
// Grid (32 px-tiles, 2 {p,g}, 16 b) = 1024 blocks.
// ---------------------------------------------------------------------------
__global__ __launch_bounds__(256) void k_mm1(
    const u16* __restrict__ xThi, const u16* __restrict__ xTlo,
    const u16* __restrict__ pAhi, const u16* __restrict__ pAlo,
    float* __restrict__ pbuf, float* __restrict__ gbuf)
{
    __shared__ short8 BldsV[4096];           // 64 KB
    char* Blds = (char*)BldsV;
    int tid = threadIdx.x, lane = tid & 63, wid = tid >> 6;
    int wm = wid >> 1, wn = wid & 1;
    int pix0 = blockIdx.x * 128;
    int by   = blockIdx.y;                   // 0: p rows, 1: g rows
    int bg   = blockIdx.z;

    const char* srcHi = (const char*)(xThi + ((size_t)bg * 4096 + pix0) * 256);
    const char* srcLo = (const char*)(xTlo + ((size_t)bg * 4096 + pix0) * 256);
    const char* aHi = (const char*)pAhi + (2 + by) * 65536 + wm * 4096 + lane * 16;
    const char* aLo = (const char*)pAlo + (2 + by) * 65536 + wm * 4096 + lane * 16;

    f32x4 acc[4][4];
    #pragma unroll
    for (int m = 0; m < 4; ++m)
        #pragma unroll
        for (int n = 0; n < 4; ++n) acc[m][n] = (f32x4)0.0f;

    STAGE16(srcHi);
    __syncthreads();
    MFMA_PASS2(aHi, aLo);            // Whi*xhi + Wlo*xhi, shared bb
    __syncthreads();                 // all waves done reading hi panel
    STAGE16(srcLo);
    __syncthreads();
    MFMA_PASS(aHi);                  // + Whi*xlo

    float* dst = (by == 0) ? pbuf : gbuf;
    int colb = pix0 + wn * 64;
    int rowb = wm * 64;              // 0..127 within p or g
    #pragma unroll
    for (int m = 0; m < 4; ++m)
        #pragma unroll
        for (int n = 0; n < 4; ++n)
            #pragma unroll
            for (int r = 0; r < 4; ++r) {
                int row = rowb + m * 16 + (lane >> 4) * 4 + r;
                int col = colb + n * 16 + (lane & 15);
                dst[((size_t)bg * 128 + row) * 4096 + col] = acc[m][n][r];
            }
}

// ---------------------------------------------------------------------------
// Kernel 3: attention dot (f32), FULL batch.  Block per (c, gi, b).
// ---------------------------------------------------------------------------
__global__ __launch_bounds__(256) void k_att(
    const float* __restrict__ pbuf, const float* __restrict__ gbuf,
    float* __restrict__ att)
{
    __shared__ float plds[HW_];
    __shared__ float glds[HW_];
    __shared__ float scr[8];
    int c  = blockIdx.x;   // 0..31
    int gi = blockIdx.y;   // 0..3
    int b  = blockIdx.z;   // 0..15
    int tid = threadIdx.x;

    const float* pp = pbuf + ((size_t)b * 128 + gi * 32 + c) * HW_;
    const float* gg = gbuf + ((size_t)b * 128 + gi * 32 + c) * HW_;

    float racc = 0.0f;
    #pragma unroll
    for (int it = 0; it < 4; ++it) {
        int i = it * 1024 + tid * 4;
        float4 pv = *(const float4*)(pp + i);
        float4 gv = *(const float4*)(gg + i);
        *(float4*)(&plds[i]) = pv;
        *(float4*)(&glds[i]) = gv;
        racc += pv.x * gv.x + pv.y * gv.y + pv.z * gv.z + pv.w * gv.w;
    }
    __syncthreads();

    float pacc = 0.0f;
    #pragma unroll 4
    for (int i = tid; i < HW_; i += 256) {
        int h = i >> 6, w = i & 63;
        int h0 = max(h - 1, 0), h1 = min(h + 1, 63);
        int w0 = max(w - 1, 0), w1 = min(w + 1, 63);
        float mp = -3.0e38f, mg = -3.0e38f;
        for (int hh = h0; hh <= h1; ++hh)
            for (int ww = w0; ww <= w1; ++ww) {
                mp = fmaxf(mp, plds[hh * 64 + ww]);
                mg = fmaxf(mg, glds[hh * 64 + ww]);
            }
        pacc += mp * mg;
    }

    #pragma unroll
    for (int off = 32; off > 0; off >>= 1) {
        racc += __shfl_down(racc, off, 64);
        pacc += __shfl_down(pacc, off, 64);
    }
    int lane = tid & 63, wid = tid >> 6;
    if (lane == 0) { scr[wid] = racc; scr[4 + wid] = pacc; }
    __syncthreads();
    if (tid == 0) {
        atomicAdd(&att[b * 8 + gi],     scr[0] + scr[1] + scr[2] + scr[3]);
        atomicAdd(&att[b * 8 + gi + 4], scr[4] + scr[5] + scr[6] + scr[7]);
    }
}

// ---------------------------------------------------------------------------
// Kernel 4: per-row softmax stats (bf16 input).  rowstat = (max, 1/expsum)
// ---------------------------------------------------------------------------
__global__ __launch_bounds__(256) void k_smax(
    const u16* __restrict__ tbuf, float2* __restrict__ rowstat)
{
    __shared__ float scr[8];
    int r = blockIdx.x;
    const u16* tr = tbuf + (size_t)r * HW_;
    int tid = threadIdx.x;
    int lane = tid & 63, wid = tid >> 6;

    float vals[16];
    float mx = -3.0e38f;
    #pragma unroll
    for (int it = 0; it < 2; ++it) {
        short8 v = *(const short8*)(tr + it * 2048 + tid * 8);
        #pragma unroll
        for (int j = 0; j < 8; ++j) {
            float f = bf2f((u16)v[j]);
            vals[it * 8 + j] = f;
            mx = fmaxf(mx, f);
        }
    }
    #pragma unroll
    for (int off = 32; off > 0; off >>= 1) mx = fmaxf(mx, __shfl_down(mx, off, 64));
    if (lane == 0) scr[wid] = mx;
    __syncthreads();
    if (tid == 0) scr[0] = fmaxf(fmaxf(scr[0], scr[1]), fmaxf(scr[2], scr[3]));
    __syncthreads();
    float m = scr[0];
    __syncthreads();

    float s = 0.0f;
    #pragma unroll
    for (int j = 0; j < 16; ++j) s += __expf(vals[j] - m);
    #pragma unroll
    for (int off = 32; off > 0; off >>= 1) s += __shfl_down(s, off, 64);
    if (lane == 0) scr[4 + wid] = s;
    __syncthreads();
    if (tid == 0) {
        float S = scr[4] + scr[5] + scr[6] + scr[7];
        rowstat[r] = make_float2(m, 1.0f / S);
    }
}

// ---------------------------------------------------------------------------
// Kernel 5: fused softmax-apply + xz mix + GN stats, in place over bf16 tbuf.
// Block per (pt 512px, gi, b); 2 px per thread; wz in 4 KB LDS.
// ---------------------------------------------------------------------------
__global__ __launch_bounds__(256) void k_xz2(
    u16* __restrict__ tbuf, const float* __restrict__ Wz,
    const float2* __restrict__ rowstat, const float* __restrict__ att,
    float* __restrict__ stats)
{
    __shared__ float wz[32][32];
    __shared__ float2 rs[32];
    __shared__ float scr[8];
    int pt  = blockIdx.x;   // 0..7  (512-pixel tile)
    int gi  = blockIdx.y;   // 0..7
    int b   = blockIdx.z;   // 0..15
    int tid = threadIdx.x;
    int px  = pt * 512 + tid * 2;

    const float* wzg = Wz + gi * 1024;
    #pragma unroll
    for (int i = 0; i < 4; ++i) {
        int idx = tid + i * 256;
        wz[idx >> 5][idx & 31] = wzg[idx];
    }
    if (tid < 32) rs[tid] = rowstat[b * 256 + gi * 32 + tid];
    __syncthreads();

    u16* base = tbuf + ((size_t)b * 256 + gi * 32) * HW_;
    float2 v[32];
    #pragma unroll
    for (int i = 0; i < 32; ++i) {
        unsigned rv = *(const unsigned*)(base + (size_t)i * HW_ + px);
        float m = rs[i].x, inv = rs[i].y;
        v[i].x = __expf(bf2f((u16)(rv & 0xffffu)) - m) * inv;
        v[i].y = __expf(bf2f((u16)(rv >> 16)) - m) * inv;
    }

    float a = att[b * 8 + gi];
    float s1 = 0.0f, s2 = 0.0f;
    #pragma unroll
    for (int o = 0; o < 32; ++o) {
        const float4* wzo = (const float4*)(&wz[o][0]);
        float ax = 0.0f, ay = 0.0f;
        #pragma unroll
        for (int j = 0; j < 8; ++j) {
            float4 w = wzo[j];
            ax = fmaf(w.x, v[4*j+0].x, ax); ay = fmaf(w.x, v[4*j+0].y, ay);
            ax = fmaf(w.y, v[4*j+1].x, ax); ay = fmaf(w.y, v[4*j+1].y, ay);
            ax = fmaf(w.z, v[4*j+2].x, ax); ay = fmaf(w.z, v[4*j+2].y, ay);
            ax = fmaf(w.w, v[4*j+3].x, ax); ay = fmaf(w.w, v[4*j+3].y, ay);
        }
        ax *= a; ay *= a;
        unsigned ov = (unsigned)f2bf(ax) | ((unsigned)f2bf(ay) << 16);
        *(unsigned*)(base + (size_t)o * HW_ + px) = ov;
        s1 += ax + ay;
        s2 = fmaf(ax, ax, fmaf(ay, ay, s2));
    }

    #pragma unroll
    for (int off = 32; off > 0; off >>= 1) {
        s1 += __shfl_down(s1, off, 64);
        s2 += __shfl_down(s2, off, 64);
    }
    int lane = tid & 63, wid = tid >> 6;
    if (lane == 0) { scr[wid] = s1; scr[4 + wid] = s2; }
    __syncthreads();
    if (tid == 0) {
        atomicAdd(&stats[(b * 8 + gi) * 2 + 0], scr[0] + scr[1] + scr[2] + scr[3]);
        atomicAdd(&stats[(b * 8 + gi) * 2 + 1], scr[4] + scr[5] + scr[6] + scr[7]);
    }
}

// ---------------------------------------------------------------------------
// Kernel 6: GroupNorm finalize + affine + residual (4 elems/thread)
// ---------------------------------------------------------------------------
__global__ __launch_bounds__(256) void k_finalize(
    const u16* __restrict__ xzbuf, const float* __restrict__ x,
    const float* __restrict__ stats, const float* __restrict__ gamma,
    const float* __restrict__ beta, float* __restrict__ out)
{
    size_t i0 = ((size_t)blockIdx.x * 256 + threadIdx.x) * 4;
    int c  = (int)((i0 >> 12) & 255);
    int bg = (int)(i0 >> 17);
    float s1 = stats[bg * 2], s2 = stats[bg * 2 + 1];
    const float invN = 1.0f / 131072.0f;
    float mu  = s1 * invN;
    float var = s2 * invN - mu * mu;
    float rs  = rsqrtf(var + EPSV);
    float ga = gamma[c], be = beta[c];

    union { unsigned long long u; u16 h[4]; } vv;
    vv.u = *(const unsigned long long*)(xzbuf + i0);
    float4 xv = *(const float4*)(x + i0);
    float4 o;
    o.x = (bf2f(vv.h[0]) - mu) * rs * ga + be + xv.x;
    o.y = (bf2f(vv.h[1]) - mu) * rs * ga + be + xv.y;
    o.z = (bf2f(vv.h[2]) - mu) * rs * ga + be + xv.z;
    o.w = (bf2f(vv.h[3]) - mu) * rs * ga + be + xv.w;
    *(float4*)(out + i0) = o;
}

// ---------------------------------------------------------------------------
extern "C" void kernel_launch(void* const* d_in, const int* in_sizes, int n_in,
                              void* d_out, int out_size, void* d_ws, size_t ws_size,
                              hipStream_t stream)
{
    const float* x     = (const float*)d_in[0];
    const float* mask  = (const float*)d_in[1];
    const float* Wt    = (const float*)d_in[2];
    const float* Wtm   = (const float*)d_in[3];
    const float* Wp    = (const float*)d_in[4];
    const float* Wg    = (const float*)d_in[5];
    const float* Wz    = (const float*)d_in[6];
    const float* gamma = (const float*)d_in[7];
    const float* beta  = (const float*)d_in[8];
    float* out = (float*)d_out;

    // workspace layout (bytes), ws_size = 256 MiB:
    //   tbuf  (bf16, full batch): 33,554,432   (t -> xz in place)
    //   xThi / xTlo (bf16, full batch): 33,554,432 each
    //   pbuf / gbuf (f32, full batch): 67,108,864 each
    //   pAhi/pAlo: 262,144 each ; tmod (f32): 262,144
    //   att/stats: 1,536 ; rowstat (float2[4096]): 32,768
    char* ws = (char*)d_ws;
    u16*   tbuf  = (u16*)(ws);
    u16*   xThi  = (u16*)(ws + 33554432);
    u16*   xTlo  = (u16*)(ws + 67108864);
    float* pbuf  = (float*)(ws + 100663296);
    float* gbuf  = (float*)(ws + 167772160);
    u16*   pAhi  = (u16*)(ws + 234881024);
    u16*   pAlo  = (u16*)(ws + 235143168);
    float* tmod  = (float*)(ws + 235405312);
    float* att   = (float*)(ws + 235667456);
    float* stats = att + 128;
    float2* rowstat = (float2*)(ws + 235669504);

    k_packA    <<<64, 256, 0, stream>>>(Wt, Wp, Wg, pAhi, pAlo);
    k_tmod_zero<<<256, 256, 0, stream>>>(mask, Wtm, tmod, att, stats);
    k_transpose<<<dim3(32, 8, 16), 256, 0, stream>>>(x, xThi, xTlo);
    k_mm0      <<<dim3(32, 2, 16), 256, 0, stream>>>(xThi, pAhi, tmod, tbuf);
    k_mm1      <<<dim3(32, 2, 16), 256, 0, stream>>>(xThi, xTlo, pAhi, pAlo, pbuf, gbuf);
    k_att      <<<dim3(32, 4, 16), 256, 0, stream>>>(pbuf, gbuf, att);
    k_smax     <<<4096, 256, 0, stream>>>(tbuf, rowstat);
    k_xz2      <<<dim3(8, 8, 16), 256, 0, stream>>>(tbuf, Wz, rowstat, att, stats);
    k_finalize <<<16384, 256, 0, stream>>>(tbuf, x, stats, gamma, beta, out);
}

// Round 14
// 179.345 us; speedup vs baseline: 1.6515x; 1.0917x over previous
//
#include <hip/hip_runtime.h>
#include <math.h>

#define B_      16
#define CIN     256
#define HW_     4096          // 64x64
#define PLANES  256
#define G_      8
#define EPSV    1e-5f

typedef unsigned short u16;
typedef __attribute__((ext_vector_type(8))) short short8;   // 8 bf16 (4 VGPRs)
typedef __attribute__((ext_vector_type(4))) float f32x4;    // MFMA acc

__device__ inline u16 f2bf(float f) {
    union { float f; unsigned u; } v; v.f = f;
    unsigned u = v.u;
    return (u16)((u + 0x7fffu + ((u >> 16) & 1u)) >> 16);   // RNE
}
__device__ inline float bf2f(u16 h) {
    union { unsigned u; float f; } v; v.u = ((unsigned)h) << 16;
    return v.f;
}

// ---------------------------------------------------------------------------
// Kernel 0a: pack Wt|Wp|Wg (512x256 f32) into MFMA A-fragment order, split
// into bf16 hi + lo (w = hi + lo, exact to ~2^-16 rel).
// slot (rt 0..3, kt 0..7, mb 0..7, lane 0..63, j 0..7):
//   row = rt*128 + mb*16 + (lane&15); k = kt*32 + (lane>>4)*8 + j
// byte offset = rt*65536 + kt*8192 + mb*1024 + lane*16
// ---------------------------------------------------------------------------
__global__ __launch_bounds__(256) void k_packA(
    const float* __restrict__ Wt, const float* __restrict__ Wp,
    const float* __restrict__ Wg,
    u16* __restrict__ pAhi, u16* __restrict__ pAlo)
{
    int t = blockIdx.x * 256 + threadIdx.x;      // 0..16383
    int lane = t & 63;
    int mb   = (t >> 6) & 7;
    int kt   = (t >> 9) & 7;
    int rt   = (t >> 12) & 3;
    int row = rt * 128 + mb * 16 + (lane & 15);
    int k0  = kt * 32 + (lane >> 4) * 8;
    const float* src;
    if      (row < 256) src = Wt + (size_t)row * 256;
    else if (row < 384) src = Wp + (size_t)(row - 256) * 256;
    else                src = Wg + (size_t)(row - 384) * 256;
    u16 hv[8], lv[8];
    #pragma unroll
    for (int j = 0; j < 8; ++j) {
        float w = src[k0 + j];
        u16 h = f2bf(w);
        hv[j] = h;
        lv[j] = f2bf(w - bf2f(h));
    }
    *(short8*)(pAhi + (size_t)t * 8) = *(short8*)hv;
    *(short8*)(pAlo + (size_t)t * 8) = *(short8*)lv;
}

// ---------------------------------------------------------------------------
// Kernel 0b: transpose x[b][256][4096] f32 -> xThi/xTlo[b][4096][256]
// bf16 hi/lo split.  FULL batch, one launch (4096 blocks).
// ---------------------------------------------------------------------------
__global__ __launch_bounds__(256) void k_transpose(
    const float* __restrict__ x, u16* __restrict__ xThi,
    u16* __restrict__ xTlo)
{
    __shared__ float tile[32][129];
    int tid = threadIdx.x;
    int px0 = blockIdx.x * 128;
    int c0  = blockIdx.y * 32;
    int bg  = blockIdx.z;

    #pragma unroll
    for (int it = 0; it < 16; ++it) {
        int flat = it * 256 + tid;
        int c_l = flat >> 7, p_l = flat & 127;
        tile[c_l][p_l] = x[((size_t)bg * 256 + c0 + c_l) * 4096 + px0 + p_l];
    }
    __syncthreads();
    #pragma unroll
    for (int it = 0; it < 8; ++it) {
        int flat = it * 256 + tid;          // 0..2047
        int p_l = flat >> 4;
        int c_l = (flat & 15) * 2;
        float v0 = tile[c_l][p_l], v1 = tile[c_l + 1][p_l];
        u16 h0 = f2bf(v0), h1 = f2bf(v1);
        u16 l0 = f2bf(v0 - bf2f(h0)), l1 = f2bf(v1 - bf2f(h1));
        size_t o = ((size_t)bg * 4096 + px0 + p_l) * 256 + c0 + c_l;
        u16 ho[2] = { h0, h1 };
        u16 lo[2] = { l0, l1 };
        *(unsigned*)(xThi + o) = *(unsigned*)ho;
        *(unsigned*)(xTlo + o) = *(unsigned*)lo;
    }
}

// ---------------------------------------------------------------------------
// Kernel 1: tmod + zero att/stats
// ---------------------------------------------------------------------------
__global__ __launch_bounds__(256) void k_tmod_zero(
    const float* __restrict__ mask, const float* __restrict__ Wtm,
    float* __restrict__ tmod, float* __restrict__ att, float* __restrict__ stats)
{
    int idx = blockIdx.x * 256 + threadIdx.x;
    float w0 = Wtm[0], w1 = Wtm[1];
    if (idx < B_ * HW_) {
        int b = idx >> 12, pix = idx & 4095;
        const float* mb = mask + (size_t)b * 2 * HW_;
        tmod[idx] = 1.0f + w0 * mb[pix] + w1 * mb[HW_ + pix];
    }
    if (blockIdx.x == 0) {
        if (threadIdx.x < 128) att[threadIdx.x] = 0.0f;
        stats[threadIdx.x] = 0.0f;
    }
}

// ---------------------------------------------------------------------------
// Shared GEMM building blocks (R9 geometry: block = 128 rows x 128 px,
// 4 waves 2x2, 64 KB LDS B-panel XOR-swizzled, natural register allocation).
// ---------------------------------------------------------------------------
#define STAGE16(SRC)                                                          \
    _Pragma("unroll")                                                         \
    for (int it = 0; it < 16; ++it) {                                         \
        int cidx = it * 256 + tid;                                            \
        int px   = cidx >> 5;                                                 \
        int boff = (cidx & 31) << 4;                                          \
        short8 v = *(const short8*)((SRC) + (size_t)px * 512 + boff);         \
        *(short8*)(Blds + px * 512 + (boff ^ ((px & 7) << 4))) = v;           \
    }

#define MFMA_PASS(ABASE)                                                      \
    _Pragma("unroll")                                                         \
    for (int kt = 0; kt < 8; ++kt) {                                          \
        short8 a[4], bb[4];                                                   \
        _Pragma("unroll")                                                     \
        for (int m = 0; m < 4; ++m)                                           \
            a[m] = *(const short8*)((ABASE) + kt * 8192 + m * 1024);          \
        int off = ((kt * 64) + ((lane >> 4) << 4)) ^ ((lane & 7) << 4);       \
        _Pragma("unroll")                                                     \
        for (int n = 0; n < 4; ++n) {                                         \
            int px = wn * 64 + n * 16 + (lane & 15);                          \
            bb[n] = *(const short8*)(Blds + px * 512 + off);                  \
        }                                                                     \
        _Pragma("unroll")                                                     \
        for (int m = 0; m < 4; ++m)                                           \
            _Pragma("unroll")                                                 \
            for (int n = 0; n < 4; ++n)                                       \
                acc[m][n] = __builtin_amdgcn_mfma_f32_16x16x32_bf16(          \
                    a[m], bb[n], acc[m][n], 0, 0, 0);                         \
    }

// Interleaved double pass: Whi and Wlo against the SAME staged panel.
#define MFMA_PASS2(AH, AL)                                                    \
    _Pragma("unroll")                                                         \
    for (int kt = 0; kt < 8; ++kt) {                                          \
        short8 ah[4], al[4], bb[4];                                           \
        _Pragma("unroll")                                                     \
        for (int m = 0; m < 4; ++m) {                                         \
            ah[m] = *(const short8*)((AH) + kt * 8192 + m * 1024);            \
            al[m] = *(const short8*)((AL) + kt * 8192 + m * 1024);            \
        }                                                                     \
        int off = ((kt * 64) + ((lane >> 4) << 4)) ^ ((lane & 7) << 4);       \
        _Pragma("unroll")                                                     \
        for (int n = 0; n < 4; ++n) {                                         \
            int px = wn * 64 + n * 16 + (lane & 15);                          \
            bb[n] = *(const short8*)(Blds + px * 512 + off);                  \
        }                                                                     \
        _Pragma("unroll")                                                     \
        for (int m = 0; m < 4; ++m)                                           \
            _Pragma("unroll")                                                 \
            for (int n = 0; n < 4; ++n) {                                     \
                acc[m][n] = __builtin_amdgcn_mfma_f32_16x16x32_bf16(          \
                    ah[m], bb[n], acc[m][n], 0, 0, 0);                        \
                acc[m][n] = __builtin_amdgcn_mfma_f32_16x16x32_bf16(          \
                    al[m], bb[n], acc[m][n], 0, 0, 0);                        \
            }                                                                 \
    }

// ---------------------------------------------------------------------------
// Kernel 2a: t-GEMM, FULL batch, 1 bf16 pass -> bf16 tbuf (* tmod).
// ---------------------------------------------------------------------------
__global__ __launch_bounds__(256) void k_mm0(
    const u16* __restrict__ xThi, const u16* __restrict__ pAhi,
    const float* __restrict__ tmod, u16* __restrict__ tbuf)
{
    __shared__ short8 BldsV[4096];           // 64 KB
    char* Blds = (char*)BldsV;
    int tid = threadIdx.x, lane = tid & 63, wid = tid >> 6;
    int wm = wid >> 1, wn = wid & 1;
    int pix0 = blockIdx.x * 128;
    int rt   = blockIdx.y;                   // 0..1 (t rows)
    int bg   = blockIdx.z;

    const char* srcHi = (const char*)(xThi + ((size_t)bg * 4096 + pix0) * 256);
    const char* aHi = (const char*)pAhi + rt * 65536 + wm * 4096 + lane * 16;

    f32x4 acc[4][4];
    #pragma unroll
    for (int m = 0; m < 4; ++m)
        #pragma unroll
        for (int n = 0; n < 4; ++n) acc[m][n] = (f32x4)0.0f;

    STAGE16(srcHi);
    __syncthreads();
    MFMA_PASS(aHi);

    int colb = pix0 + wn * 64;
    int rowb = rt * 128 + wm * 64;
    float tm[4];
    #pragma unroll
    for (int n = 0; n < 4; ++n) tm[n] = tmod[bg * 4096 + colb + n * 16 + (lane & 15)];
    #pragma unroll
    for (int m = 0; m < 4; ++m)
        #pragma unroll
        for (int n = 0; n < 4; ++n)
            #pragma unroll
            for (int r = 0; r < 4; ++r) {
                int row = rowb + m * 16 + (lane >> 4) * 4 + r;
                int col = colb + n * 16 + (lane & 15);
                tbuf[((size_t)bg * 256 + row) * 4096 + col] = f2bf(acc[m][n][r] * tm[n]);
            }
}

// ---------------------------------------------------------------------------
// Kernel 2b: p/g-GEMM, FULL batch, f32-exact -> f32 pbuf/gbuf.
// Phase 1: interleaved (Whi + Wlo) x xhi.  Phase 2: restage lo, + Whi x xlo.
// ---------------------------------------------------------------------------
__global__ __launch_bounds__(256) void k_mm1(
    const u16* __restrict__ xThi, const u16* __restrict__ xTlo,
    const u16* __restrict__ pAhi, const u16* __restrict__ pAlo,
    float* __restrict__ pbuf, float* __restrict__ gbuf)
{
    __shared__ short8 BldsV[4096];           // 64 KB
    char* Blds = (char*)BldsV;
    int tid = threadIdx.x, lane = tid & 63, wid = tid >> 6;
    int wm = wid >> 1, wn = wid & 1;
    int pix0 = blockIdx.x * 128;
    int by   = blockIdx.y;                   // 0: p rows, 1: g rows
    int bg   = blockIdx.z;

    const char* srcHi = (const char*)(xThi + ((size_t)bg * 4096 + pix0) * 256);
    const char* srcLo = (const char*)(xTlo + ((size_t)bg * 4096 + pix0) * 256);
    const char* aHi = (const char*)pAhi + (2 + by) * 65536 + wm * 4096 + lane * 16;
    const char* aLo = (const char*)pAlo + (2 + by) * 65536 + wm * 4096 + lane * 16;

    f32x4 acc[4][4];
    #pragma unroll
    for (int m = 0; m < 4; ++m)
        #pragma unroll
        for (int n = 0; n < 4; ++n) acc[m][n] = (f32x4)0.0f;

    STAGE16(srcHi);
    __syncthreads();
    MFMA_PASS2(aHi, aLo);            // Whi*xhi + Wlo*xhi, shared bb
    __syncthreads();                 // all waves done reading hi panel
    STAGE16(srcLo);
    __syncthreads();
    MFMA_PASS(aHi);                  // + Whi*xlo

    float* dst = (by == 0) ? pbuf : gbuf;
    int colb = pix0 + wn * 64;
    int rowb = wm * 64;              // 0..127 within p or g
    #pragma unroll
    for (int m = 0; m < 4; ++m)
        #pragma unroll
        for (int n = 0; n < 4; ++n)
            #pragma unroll
            for (int r = 0; r < 4; ++r) {
                int row = rowb + m * 16 + (lane >> 4) * 4 + r;
                int col = colb + n * 16 + (lane & 15);
                dst[((size_t)bg * 128 + row) * 4096 + col] = acc[m][n][r];
            }
}

// ---------------------------------------------------------------------------
// Kernel 3: attention dot (f32), separable 3x3 maxpool.
// Block per (c, gi, b).  Thread owns 16 contiguous px (quarter-row) in regs:
//   hmax in registers (halo via LDS), hmax rows stored to LDS (b128),
//   vertical max reads up/down hmax rows (b128).  Raw dot from regs.
// ---------------------------------------------------------------------------
__global__ __launch_bounds__(256) void k_att(
    const float* __restrict__ pbuf, const float* __restrict__ gbuf,
    float* __restrict__ att)
{
    __shared__ float hmp[HW_];       // 16 KB: hmax of p
    __shared__ float hmg[HW_];       // 16 KB: hmax of g
    __shared__ float halo[256][4];   // v0/v15 of p and g per thread
    __shared__ float scr[8];
    int c  = blockIdx.x;   // 0..31
    int gi = blockIdx.y;   // 0..3
    int b  = blockIdx.z;   // 0..15
    int tid = threadIdx.x;
    int tq = tid & 3;      // quarter within image row
    int r  = tid >> 2;     // image row 0..63
    int px0 = tid * 16;

    const float* pp = pbuf + ((size_t)b * 128 + gi * 32 + c) * HW_ + px0;
    const float* gg = gbuf + ((size_t)b * 128 + gi * 32 + c) * HW_ + px0;

    float pv[16], gv[16];
    float racc = 0.0f;
    #pragma unroll
    for (int i = 0; i < 4; ++i) {
        float4 p4 = *(const float4*)(pp + i * 4);
        float4 g4 = *(const float4*)(gg + i * 4);
        pv[4*i+0] = p4.x; pv[4*i+1] = p4.y; pv[4*i+2] = p4.z; pv[4*i+3] = p4.w;
        gv[4*i+0] = g4.x; gv[4*i+1] = g4.y; gv[4*i+2] = g4.z; gv[4*i+3] = g4.w;
        racc += p4.x * g4.x + p4.y * g4.y + p4.z * g4.z + p4.w * g4.w;
    }
    halo[tid][0] = pv[0]; halo[tid][1] = pv[15];
    halo[tid][2] = gv[0]; halo[tid][3] = gv[15];
    __syncthreads();

    float pL = (tq > 0) ? halo[tid - 1][1] : pv[0];
    float pR = (tq < 3) ? halo[tid + 1][0] : pv[15];
    float gL = (tq > 0) ? halo[tid - 1][3] : gv[0];
    float gR = (tq < 3) ? halo[tid + 1][2] : gv[15];

    float hp[16], hg[16];
    hp[0] = fmaxf(fmaxf(pL, pv[0]), pv[1]);
    hg[0] = fmaxf(fmaxf(gL, gv[0]), gv[1]);
    #pragma unroll
    for (int j = 1; j < 15; ++j) {
        hp[j] = fmaxf(fmaxf(pv[j-1], pv[j]), pv[j+1]);
        hg[j] = fmaxf(fmaxf(gv[j-1], gv[j]), gv[j+1]);
    }
    hp[15] = fmaxf(fmaxf(pv[14], pv[15]), pR);
    hg[15] = fmaxf(fmaxf(gv[14], gv[15]), gR);

    #pragma unroll
    for (int i = 0; i < 4; ++i) {
        *(float4*)(&hmp[px0 + i * 4]) = make_float4(hp[4*i], hp[4*i+1], hp[4*i+2], hp[4*i+3]);
        *(float4*)(&hmg[px0 + i * 4]) = make_float4(hg[4*i], hg[4*i+1], hg[4*i+2], hg[4*i+3]);
    }
    __syncthreads();

    int up = (r > 0)  ? px0 - 64 : px0;   // clamp at top (max with self = no-op)
    int dn = (r < 63) ? px0 + 64 : px0;   // clamp at bottom
    float pacc = 0.0f;
    #pragma unroll
    for (int i = 0; i < 4; ++i) {
        float4 pu = *(const float4*)(&hmp[up + i * 4]);
        float4 pd = *(const float4*)(&hmp[dn + i * 4]);
        float4 gu = *(const float4*)(&hmg[up + i * 4]);
        float4 gd = *(const float4*)(&hmg[dn + i * 4]);
        float mpx, mgx;
        mpx = fmaxf(fmaxf(pu.x, hp[4*i+0]), pd.x); mgx = fmaxf(fmaxf(gu.x, hg[4*i+0]), gd.x); pacc += mpx * mgx;
        mpx = fmaxf(fmaxf(pu.y, hp[4*i+1]), pd.y); mgx = fmaxf(fmaxf(gu.y, hg[4*i+1]), gd.y); pacc += mpx * mgx;
        mpx = fmaxf(fmaxf(pu.z, hp[4*i+2]), pd.z); mgx = fmaxf(fmaxf(gu.z, hg[4*i+2]), gd.z); pacc += mpx * mgx;
        mpx = fmaxf(fmaxf(pu.w, hp[4*i+3]), pd.w); mgx = fmaxf(fmaxf(gu.w, hg[4*i+3]), gd.w); pacc += mpx * mgx;
    }

    #pragma unroll
    for (int off = 32; off > 0; off >>= 1) {
        racc += __shfl_down(racc, off, 64);
        pacc += __shfl_down(pacc, off, 64);
    }
    int lane = tid & 63, wid = tid >> 6;
    if (lane == 0) { scr[wid] = racc; scr[4 + wid] = pacc; }
    __syncthreads();
    if (tid == 0) {
        atomicAdd(&att[b * 8 + gi],     scr[0] + scr[1] + scr[2] + scr[3]);
        atomicAdd(&att[b * 8 + gi + 4], scr[4] + scr[5] + scr[6] + scr[7]);
    }
}

// ---------------------------------------------------------------------------
// Kernel 4: per-row softmax stats (bf16 input).  rowstat = (max, 1/expsum)
// ---------------------------------------------------------------------------
__global__ __launch_bounds__(256) void k_smax(
    const u16* __restrict__ tbuf, float2* __restrict__ rowstat)
{
    __shared__ float scr[8];
    int r = blockIdx.x;
    const u16* tr = tbuf + (size_t)r * HW_;
    int tid = threadIdx.x;
    int lane = tid & 63, wid = tid >> 6;

    float vals[16];
    float mx = -3.0e38f;
    #pragma unroll
    for (int it = 0; it < 2; ++it) {
        short8 v = *(const short8*)(tr + it * 2048 + tid * 8);
        #pragma unroll
        for (int j = 0; j < 8; ++j) {
            float f = bf2f((u16)v[j]);
            vals[it * 8 + j] = f;
            mx = fmaxf(mx, f);
        }
    }
    #pragma unroll
    for (int off = 32; off > 0; off >>= 1) mx = fmaxf(mx, __shfl_down(mx, off, 64));
    if (lane == 0) scr[wid] = mx;
    __syncthreads();
    if (tid == 0) scr[0] = fmaxf(fmaxf(scr[0], scr[1]), fmaxf(scr[2], scr[3]));
    __syncthreads();
    float m = scr[0];
    __syncthreads();

    float s = 0.0f;
    #pragma unroll
    for (int j = 0; j < 16; ++j) s += __expf(vals[j] - m);
    #pragma unroll
    for (int off = 32; off > 0; off >>= 1) s += __shfl_down(s, off, 64);
    if (lane == 0) scr[4 + wid] = s;
    __syncthreads();
    if (tid == 0) {
        float S = scr[4] + scr[5] + scr[6] + scr[7];
        rowstat[r] = make_float2(m, 1.0f / S);
    }
}

// ---------------------------------------------------------------------------
// Kernel 5: fused softmax-apply + xz mix + GN stats, in place over bf16 tbuf.
// ---------------------------------------------------------------------------
__global__ __launch_bounds__(256) void k_xz2(
    u16* __restrict__ tbuf, const float* __restrict__ Wz,
    const float2* __restrict__ rowstat, const float* __restrict__ att,
    float* __restrict__ stats)
{
    __shared__ float wz[32][32];
    __shared__ float2 rs[32];
    __shared__ float scr[8];
    int pt  = blockIdx.x;   // 0..7  (512-pixel tile)
    int gi  = blockIdx.y;   // 0..7
    int b   = blockIdx.z;   // 0..15
    int tid = threadIdx.x;
    int px  = pt * 512 + tid * 2;

    const float* wzg = Wz + gi * 1024;
    #pragma unroll
    for (int i = 0; i < 4; ++i) {
        int idx = tid + i * 256;
        wz[idx >> 5][idx & 31] = wzg[idx];
    }
    if (tid < 32) rs[tid] = rowstat[b * 256 + gi * 32 + tid];
    __syncthreads();

    u16* base = tbuf + ((size_t)b * 256 + gi * 32) * HW_;
    float2 v[32];
    #pragma unroll
    for (int i = 0; i < 32; ++i) {
        unsigned rv = *(const unsigned*)(base + (size_t)i * HW_ + px);
        float m = rs[i].x, inv = rs[i].y;
        v[i].x = __expf(bf2f((u16)(rv & 0xffffu)) - m) * inv;
        v[i].y = __expf(bf2f((u16)(rv >> 16)) - m) * inv;
    }

    float a = att[b * 8 + gi];
    float s1 = 0.0f, s2 = 0.0f;
    #pragma unroll
    for (int o = 0; o < 32; ++o) {
        const float4* wzo = (const float4*)(&wz[o][0]);
        float ax = 0.0f, ay = 0.0f;
        #pragma unroll
        for (int j = 0; j < 8; ++j) {
            float4 w = wzo[j];
            ax = fmaf(w.x, v[4*j+0].x, ax); ay = fmaf(w.x, v[4*j+0].y, ay);
            ax = fmaf(w.y, v[4*j+1].x, ax); ay = fmaf(w.y, v[4*j+1].y, ay);
            ax = fmaf(w.z, v[4*j+2].x, ax); ay = fmaf(w.z, v[4*j+2].y, ay);
            ax = fmaf(w.w, v[4*j+3].x, ax); ay = fmaf(w.w, v[4*j+3].y, ay);
        }
        ax *= a; ay *= a;
        unsigned ov = (unsigned)f2bf(ax) | ((unsigned)f2bf(ay) << 16);
        *(unsigned*)(base + (size_t)o * HW_ + px) = ov;
        s1 += ax + ay;
        s2 = fmaf(ax, ax, fmaf(ay, ay, s2));
    }

    #pragma unroll
    for (int off = 32; off > 0; off >>= 1) {
        s1 += __shfl_down(s1, off, 64);
        s2 += __shfl_down(s2, off, 64);
    }
    int lane = tid & 63, wid = tid >> 6;
    if (lane == 0) { scr[wid] = s1; scr[4 + wid] = s2; }
    __syncthreads();
    if (tid == 0) {
        atomicAdd(&stats[(b * 8 + gi) * 2 + 0], scr[0] + scr[1] + scr[2] + scr[3]);
        atomicAdd(&stats[(b * 8 + gi) * 2 + 1], scr[4] + scr[5] + scr[6] + scr[7]);
    }
}

// ---------------------------------------------------------------------------
// Kernel 6: GroupNorm finalize + affine + residual (4 elems/thread)
// ---------------------------------------------------------------------------
__global__ __launch_bounds__(256) void k_finalize(
    const u16* __restrict__ xzbuf, const float* __restrict__ x,
    const float* __restrict__ stats, const float* __restrict__ gamma,
    const float* __restrict__ beta, float* __restrict__ out)
{
    size_t i0 = ((size_t)blockIdx.x * 256 + threadIdx.x) * 4;
    int c  = (int)((i0 >> 12) & 255);
    int bg = (int)(i0 >> 17);
    float s1 = stats[bg * 2], s2 = stats[bg * 2 + 1];
    const float invN = 1.0f / 131072.0f;
    float mu  = s1 * invN;
    float var = s2 * invN - mu * mu;
    float rs  = rsqrtf(var + EPSV);
    float ga = gamma[c], be = beta[c];

    union { unsigned long long u; u16 h[4]; } vv;
    vv.u = *(const unsigned long long*)(xzbuf + i0);
    float4 xv = *(const float4*)(x + i0);
    float4 o;
    o.x = (bf2f(vv.h[0]) - mu) * rs * ga + be + xv.x;
    o.y = (bf2f(vv.h[1]) - mu) * rs * ga + be + xv.y;
    o.z = (bf2f(vv.h[2]) - mu) * rs * ga + be + xv.z;
    o.w = (bf2f(vv.h[3]) - mu) * rs * ga + be + xv.w;
    *(float4*)(out + i0) = o;
}

// ---------------------------------------------------------------------------
extern "C" void kernel_launch(void* const* d_in, const int* in_sizes, int n_in,
                              void* d_out, int out_size, void* d_ws, size_t ws_size,
                              hipStream_t stream)
{
    const float* x     = (const float*)d_in[0];
    const float* mask  = (const float*)d_in[1];
    const float* Wt    = (const float*)d_in[2];
    const float* Wtm   = (const float*)d_in[3];
    const float* Wp    = (const float*)d_in[4];
    const float* Wg    = (const float*)d_in[5];
    const float* Wz    = (const float*)d_in[6];
    const float* gamma = (const float*)d_in[7];
    const float* beta  = (const float*)d_in[8];
    float* out = (float*)d_out;

    // workspace layout (bytes), ws_size = 256 MiB:
    //   tbuf  (bf16, full batch): 33,554,432   (t -> xz in place)
    //   xThi / xTlo (bf16, full batch): 33,554,432 each
    //   pbuf / gbuf (f32, full batch): 67,108,864 each
    //   pAhi/pAlo: 262,144 each ; tmod (f32): 262,144
    //   att/stats: 1,536 ; rowstat (float2[4096]): 32,768
    char* ws = (char*)d_ws;
    u16*   tbuf  = (u16*)(ws);
    u16*   xThi  = (u16*)(ws + 33554432);
    u16*   xTlo  = (u16*)(ws + 67108864);
    float* pbuf  = (float*)(ws + 100663296);
    float* gbuf  = (float*)(ws + 167772160);
    u16*   pAhi  = (u16*)(ws + 234881024);
    u16*   pAlo  = (u16*)(ws + 235143168);
    float* tmod  = (float*)(ws + 235405312);
    float* att   = (float*)(ws + 235667456);
    float* stats = att + 128;
    float2* rowstat = (float2*)(ws + 235669504);

    k_packA    <<<64, 256, 0, stream>>>(Wt, Wp, Wg, pAhi, pAlo);
    k_tmod_zero<<<256, 256, 0, stream>>>(mask, Wtm, tmod, att, stats);
    k_transpose<<<dim3(32, 8, 16), 256, 0, stream>>>(x, xThi, xTlo);
    k_mm0      <<<dim3(32, 2, 16), 256, 0, stream>>>(xThi, pAhi, tmod, tbuf);
    k_mm1      <<<dim3(32, 2, 16), 256, 0, stream>>>(xThi, xTlo, pAhi, pAlo, pbuf, gbuf);
    k_att      <<<dim3(32, 4, 16), 256, 0, stream>>>(pbuf, gbuf, att);
    k_smax     <<<4096, 256, 0, stream>>>(tbuf, rowstat);
    k_xz2      <<<dim3(8, 8, 16), 256, 0, stream>>>(tbuf, Wz, rowstat, att, stats);
    k_finalize <<<16384, 256, 0, stream>>>(tbuf, x, stats, gamma, beta, out);
}